// Round 10
// baseline (431.346 us; speedup 1.0000x reference)
//
#include <hip/hip_runtime.h>
#include <cstdint>
#include <cstddef>

// ---------------- preprocessing kernels ----------------

__global__ __launch_bounds__(256) void count_kernel(const int* __restrict__ dst,
                                                    int* __restrict__ counts, int e) {
  int i = blockIdx.x * 256 + threadIdx.x;
  if (i < e) atomicAdd(&counts[dst[i]], 1);
}

__global__ __launch_bounds__(256) void dinv_kernel(const int* __restrict__ counts,
                                                   float* __restrict__ dinv, int n) {
  int i = blockIdx.x * 256 + threadIdx.x;
  if (i < n) dinv[i] = rsqrtf((float)(counts[i] + 1));  // +1 = self loop
}

__global__ __launch_bounds__(256) void scan1_kernel(const int* __restrict__ counts,
                                                    int* __restrict__ bsum, int n) {
  __shared__ int lds[256];
  int tid = threadIdx.x;
  int i = blockIdx.x * 256 + tid;
  lds[tid] = (i < n) ? counts[i] : 0;
  __syncthreads();
  for (int off = 128; off > 0; off >>= 1) {
    if (tid < off) lds[tid] += lds[tid + off];
    __syncthreads();
  }
  if (tid == 0) bsum[blockIdx.x] = lds[0];
}

// exclusive scan of nb (<=256) block sums, in place
__global__ __launch_bounds__(256) void scan2_kernel(int* __restrict__ bsum, int nb) {
  __shared__ int lds[256];
  int tid = threadIdx.x;
  int v = (tid < nb) ? bsum[tid] : 0;
  lds[tid] = v;
  __syncthreads();
  for (int off = 1; off < 256; off <<= 1) {
    int t = (tid >= off) ? lds[tid - off] : 0;
    __syncthreads();
    lds[tid] += t;
    __syncthreads();
  }
  if (tid < nb) bsum[tid] = lds[tid] - v;  // exclusive
}

__global__ __launch_bounds__(256) void scan3_kernel(const int* __restrict__ counts,
                                                    const int* __restrict__ bsum,
                                                    int* __restrict__ offsets, int n) {
  __shared__ int lds[256];
  int tid = threadIdx.x;
  int i = blockIdx.x * 256 + tid;
  int v = (i < n) ? counts[i] : 0;
  lds[tid] = v;
  __syncthreads();
  for (int off = 1; off < 256; off <<= 1) {
    int t = (tid >= off) ? lds[tid - off] : 0;
    __syncthreads();
    lds[tid] += t;
    __syncthreads();
  }
  if (i < n) offsets[i] = bsum[blockIdx.x] + lds[tid] - v;  // exclusive offsets
}

// builds CSR by dst with (src, weight) packed as int2;
// afterwards offsets[v] == segment END (start = end - counts[v])
__global__ __launch_bounds__(256) void scatter_kernel(const int* __restrict__ src,
                                                      const int* __restrict__ dst,
                                                      const float* __restrict__ dinv,
                                                      int* __restrict__ offsets,
                                                      int2* __restrict__ csr_sw, int e) {
  int i = blockIdx.x * 256 + threadIdx.x;
  if (i < e) {
    int d = dst[i], s = src[i];
    int pos = atomicAdd(&offsets[d], 1);
    csr_sw[pos] = make_int2(s, __float_as_int(dinv[s] * dinv[d]));
  }
}

// ---------------- GEMM: T[M x BN] = X[M x 128] @ W[128 x BN] ----------------
// Full-K one-barrier design: stage X-tile TRANSPOSED (xs[K][BM]) + entire W
// (ws[K][BN]) in LDS once, then a barrier-free k-loop. Each thread owns a
// 4x4 register tile: per k only 2x ds_read_b128 for 16 FMAs.

template <int BM, int BN>
__global__ __launch_bounds__(256) void gemm_kernel(const float* __restrict__ X,
                                                   const float* __restrict__ W,
                                                   float* __restrict__ T, int M) {
  constexpr int K = 128;
  static_assert(BM * BN == 4096, "4x4 tile x 256 threads");
  __shared__ float xs[K][BM];   // X^T tile
  __shared__ float ws[K][BN];   // full W

  int tid = threadIdx.x;
  int row0 = blockIdx.x * BM;

  {
    constexpr int TPR = 256 / BM;   // threads per row
    int r = tid / TPR;
    int lw = tid % TPR;
    int grow = row0 + r;
    if (grow >= M) grow = M - 1;    // clamp; garbage rows guarded at store
    const float* xp = &X[(size_t)grow * K];
#pragma unroll
    for (int u = 0; u < K / (4 * TPR); ++u) {
      int k = (lw + u * TPR) * 4;
      float4 v = *(const float4*)&xp[k];
      xs[k + 0][r] = v.x;
      xs[k + 1][r] = v.y;
      xs[k + 2][r] = v.z;
      xs[k + 3][r] = v.w;
    }
  }
  {
    const float4* wsrc = (const float4*)W;
    float4* wdst = (float4*)&ws[0][0];
#pragma unroll
    for (int u = 0; u < (K * BN) / 1024; ++u)
      wdst[tid + u * 256] = wsrc[tid + u * 256];
  }
  __syncthreads();

  int r0 = (tid % (BM / 4)) * 4;
  int c0 = (tid / (BM / 4)) * 4;
  float acc[4][4];
#pragma unroll
  for (int i = 0; i < 4; ++i)
#pragma unroll
    for (int j = 0; j < 4; ++j) acc[i][j] = 0.f;

#pragma unroll 8
  for (int k = 0; k < K; ++k) {
    float4 a = *(const float4*)&xs[k][r0];
    float4 b = *(const float4*)&ws[k][c0];
    float av[4] = {a.x, a.y, a.z, a.w};
    float bv[4] = {b.x, b.y, b.z, b.w};
#pragma unroll
    for (int i = 0; i < 4; ++i)
#pragma unroll
      for (int j = 0; j < 4; ++j) acc[i][j] += av[i] * bv[j];
  }

#pragma unroll
  for (int i = 0; i < 4; ++i) {
    int grow = row0 + r0 + i;
    if (grow < M) {
      float4 o = {acc[i][0], acc[i][1], acc[i][2], acc[i][3]};
      *(float4*)&T[(size_t)grow * BN + c0] = o;
    }
  }
}

// ---------------- aggregation: O[v] = dinv[v]^2*T[v] + sum_in w*T[src] + b --------
// XCD-pinned feature chunking: R9 counters showed agg is bound by L2-miss
// fabric traffic (FETCH 144 MB for a 25.6 MB working set -> per-XCD L2 too
// small). Split features into CHUNKS slices of 16 floats (64 B) and pin
// chunk = f(blockIdx % 8) so each XCD's L2 only holds ONE 3.2 MB slice of T
// -> gathers become L2 hits; fabric traffic ~70 MB instead of 144 MB.
// PARTS = 8/CHUNKS node-range partitions fill the remaining slot bits.
// 4 lanes/node (one float4 each), 64 nodes/block, 4-wide edge unroll.

template <int F, int CHUNKS, bool RELU>
__global__ __launch_bounds__(256) void agg_kernel(const float* __restrict__ T,
                                                  const int2* __restrict__ csr_sw,
                                                  const int* __restrict__ offsets,
                                                  const int* __restrict__ counts,
                                                  const float* __restrict__ dinv,
                                                  const float* __restrict__ bias,
                                                  float* __restrict__ O, int n, int npp) {
  constexpr int FCH = F / CHUNKS;   // 16 floats = 64 B slice
  constexpr int LPN = FCH / 4;      // 4 lanes per node
  constexpr int NPB = 256 / LPN;    // 64 nodes per block
  constexpr int PARTS = 8 / CHUNKS;

  int slot = blockIdx.x & 7;        // -> XCD (round-robin assumption)
  int bsub = blockIdx.x >> 3;
  int chunk = slot / PARTS;
  int part = slot % PARTS;

  int tid = threadIdx.x;
  int lane = tid % LPN;
  int v = part * npp + bsub * NPB + tid / LPN;
  int vmax = min(n, (part + 1) * npp);
  if (v >= vmax) return;

  int fo = chunk * FCH + lane * 4;  // feature offset of this lane's float4

  float dv = dinv[v];
  float sw = dv * dv;               // self-loop weight
  float4 t = *(const float4*)&T[(size_t)v * F + fo];
  float ax = sw * t.x, ay = sw * t.y, az = sw * t.z, aw = sw * t.w;

  int end = offsets[v];
  int i = end - counts[v];
  for (; i + 4 <= end; i += 4) {
    int2 p0 = csr_sw[i + 0];
    int2 p1 = csr_sw[i + 1];
    int2 p2 = csr_sw[i + 2];
    int2 p3 = csr_sw[i + 3];
    float4 u0 = *(const float4*)&T[(size_t)p0.x * F + fo];
    float4 u1 = *(const float4*)&T[(size_t)p1.x * F + fo];
    float4 u2 = *(const float4*)&T[(size_t)p2.x * F + fo];
    float4 u3 = *(const float4*)&T[(size_t)p3.x * F + fo];
    float w0 = __int_as_float(p0.y), w1 = __int_as_float(p1.y);
    float w2 = __int_as_float(p2.y), w3 = __int_as_float(p3.y);
    ax += w0 * u0.x; ay += w0 * u0.y; az += w0 * u0.z; aw += w0 * u0.w;
    ax += w1 * u1.x; ay += w1 * u1.y; az += w1 * u1.z; aw += w1 * u1.w;
    ax += w2 * u2.x; ay += w2 * u2.y; az += w2 * u2.z; aw += w2 * u2.w;
    ax += w3 * u3.x; ay += w3 * u3.y; az += w3 * u3.z; aw += w3 * u3.w;
  }
  for (; i < end; ++i) {
    int2 p = csr_sw[i];
    float w = __int_as_float(p.y);
    float4 u = *(const float4*)&T[(size_t)p.x * F + fo];
    ax += w * u.x; ay += w * u.y; az += w * u.z; aw += w * u.w;
  }
  float4 bb = *(const float4*)&bias[fo];
  ax += bb.x; ay += bb.y; az += bb.z; aw += bb.w;
  if (RELU) {
    ax = fmaxf(ax, 0.f); ay = fmaxf(ay, 0.f);
    az = fmaxf(az, 0.f); aw = fmaxf(aw, 0.f);
  }
  float4 o; o.x = ax; o.y = ay; o.z = az; o.w = aw;
  *(float4*)&O[(size_t)v * F + fo] = o;
}

// ---------------- pooling + softmax ----------------

// segmented mean-pool: batch[] is SORTED, so each wave owns 64 contiguous
// nodes, accumulates per-lane in a register, and flushes to global only on
// batch-id change (or at span end). ~60K atomics total vs 3.2M naive.
__global__ __launch_bounds__(256) void pool_kernel(const float* __restrict__ h3,
                                                   const int* __restrict__ batch,
                                                   float* __restrict__ pooled,
                                                   float* __restrict__ gcnt, int n) {
  constexpr int NPW = 64;  // nodes per wave
  int lane = threadIdx.x & 63;
  int wave = threadIdx.x >> 6;
  int v0 = (blockIdx.x * 4 + wave) * NPW;
  if (v0 >= n) return;
  int vend = min(v0 + NPW, n);

  float acc = 0.f;
  int cnt = 0;
  int bcur = batch[v0];
  for (int v = v0; v < vend; ++v) {
    int b = batch[v];
    if (b != bcur) {
      atomicAdd(&pooled[bcur * 64 + lane], acc);
      if (lane == 0) atomicAdd(&gcnt[bcur], (float)cnt);
      acc = 0.f; cnt = 0; bcur = b;
    }
    acc += h3[(size_t)v * 64 + lane];
    ++cnt;
  }
  atomicAdd(&pooled[bcur * 64 + lane], acc);
  if (lane == 0) atomicAdd(&gcnt[bcur], (float)cnt);
}

__global__ __launch_bounds__(64) void softmax_kernel(const float* __restrict__ pooled,
                                                     const float* __restrict__ gcnt,
                                                     float* __restrict__ out) {
  int g = blockIdx.x;
  int lane = threadIdx.x;
  float c = fmaxf(gcnt[g], 1.0f);
  float v = pooled[g * 64 + lane] / c;
  float m = v;
#pragma unroll
  for (int off = 32; off >= 1; off >>= 1) m = fmaxf(m, __shfl_xor(m, off));
  float e = expf(v - m);
  float s = e;
#pragma unroll
  for (int off = 32; off >= 1; off >>= 1) s += __shfl_xor(s, off);
  out[g * 64 + lane] = e / s;
}

// ---------------- launch ----------------

extern "C" void kernel_launch(void* const* d_in, const int* in_sizes, int n_in,
                              void* d_out, int out_size, void* d_ws, size_t ws_size,
                              hipStream_t stream) {
  const float* x  = (const float*)d_in[0];
  const int* edge = (const int*)d_in[1];
  const int* batch = (const int*)d_in[2];
  const float* W0 = (const float*)d_in[3];
  const float* b0 = (const float*)d_in[4];
  const float* W1 = (const float*)d_in[5];
  const float* b1 = (const float*)d_in[6];
  const float* W2 = (const float*)d_in[7];
  const float* b2 = (const float*)d_in[8];
  float* out = (float*)d_out;

  const int N = in_sizes[2];      // 50000 nodes (batch vector length)
  const int E = in_sizes[1] / 2;  // 600000 edges
  const int* esrc = edge;
  const int* edst = edge + E;

  char* p = (char*)d_ws;
  auto alloc = [&](size_t bytes) {
    char* r = p;
    p += (bytes + 255) & ~(size_t)255;
    return r;
  };
  int*   counts  = (int*)alloc((size_t)N * 4);
  int*   offsets = (int*)alloc((size_t)N * 4);
  float* dinv    = (float*)alloc((size_t)N * 4);
  int*   bsum    = (int*)alloc(256 * 4);
  int2*  csr_sw  = (int2*)alloc((size_t)E * 8);
  float* bufA    = (float*)alloc((size_t)N * 128 * 4);
  float* bufB    = (float*)alloc((size_t)N * 128 * 4);
  float* pooled  = (float*)alloc(128 * 64 * 4);
  float* gcnt    = (float*)alloc(128 * 4);

  int nbN = (N + 255) / 256;  // 196 (<=256, required by scan2)
  int nbE = (E + 255) / 256;

  hipMemsetAsync(counts, 0, (size_t)N * 4, stream);
  hipMemsetAsync(pooled, 0, 128 * 64 * 4, stream);
  hipMemsetAsync(gcnt, 0, 128 * 4, stream);

  count_kernel<<<nbE, 256, 0, stream>>>(edst, counts, E);
  dinv_kernel<<<nbN, 256, 0, stream>>>(counts, dinv, N);
  scan1_kernel<<<nbN, 256, 0, stream>>>(counts, bsum, N);
  scan2_kernel<<<1, 256, 0, stream>>>(bsum, nbN);
  scan3_kernel<<<nbN, 256, 0, stream>>>(counts, bsum, offsets, N);
  scatter_kernel<<<nbE, 256, 0, stream>>>(esrc, edst, dinv, offsets, csr_sw, E);

  // agg grids: 8 slots (XCD-pinned chunk/part) x blocks covering the node range
  int npp128 = N;                             // CHUNKS=8 -> PARTS=1
  int nb128 = 8 * ((npp128 + 63) / 64);
  int npp64 = (N + 1) / 2;                    // CHUNKS=4 -> PARTS=2
  int nb64 = 8 * ((npp64 + 63) / 64);

  // layer 1: t = x @ W0 ; h1 = relu(A t + b0)
  gemm_kernel<32, 128><<<(N + 31) / 32, 256, 0, stream>>>(x, W0, bufA, N);
  agg_kernel<128, 8, true><<<nb128, 256, 0, stream>>>(bufA, csr_sw, offsets,
                                                      counts, dinv, b0, bufB, N, npp128);
  // layer 2
  gemm_kernel<32, 128><<<(N + 31) / 32, 256, 0, stream>>>(bufB, W1, bufA, N);
  agg_kernel<128, 8, true><<<nb128, 256, 0, stream>>>(bufA, csr_sw, offsets,
                                                      counts, dinv, b1, bufB, N, npp128);
  // layer 3 (64-wide, no relu)
  gemm_kernel<64, 64><<<(N + 63) / 64, 256, 0, stream>>>(bufB, W2, bufA, N);
  agg_kernel<64, 4, false><<<nb64, 256, 0, stream>>>(bufA, csr_sw, offsets,
                                                     counts, dinv, b2, bufB, N, npp64);

  // mean pool + softmax
  pool_kernel<<<(N + 255) / 256, 256, 0, stream>>>(bufB, batch, pooled, gcnt, N);
  softmax_kernel<<<128, 64, 0, stream>>>(pooled, gcnt, out);
}

// Round 12
// 335.657 us; speedup vs baseline: 1.2851x; 1.2851x over previous
//
#include <hip/hip_runtime.h>
#include <cstdint>
#include <cstddef>

typedef unsigned int uint32;

// ---------------- preprocessing kernels ----------------

__global__ __launch_bounds__(256) void count_kernel(const int* __restrict__ dst,
                                                    int* __restrict__ counts, int e) {
  int i = blockIdx.x * 256 + threadIdx.x;
  if (i < e) atomicAdd(&counts[dst[i]], 1);
}

__global__ __launch_bounds__(256) void dinv_kernel(const int* __restrict__ counts,
                                                   float* __restrict__ dinv, int n) {
  int i = blockIdx.x * 256 + threadIdx.x;
  if (i < n) dinv[i] = rsqrtf((float)(counts[i] + 1));  // +1 = self loop
}

__global__ __launch_bounds__(256) void scan1_kernel(const int* __restrict__ counts,
                                                    int* __restrict__ bsum, int n) {
  __shared__ int lds[256];
  int tid = threadIdx.x;
  int i = blockIdx.x * 256 + tid;
  lds[tid] = (i < n) ? counts[i] : 0;
  __syncthreads();
  for (int off = 128; off > 0; off >>= 1) {
    if (tid < off) lds[tid] += lds[tid + off];
    __syncthreads();
  }
  if (tid == 0) bsum[blockIdx.x] = lds[0];
}

// exclusive scan of nb (<=256) block sums, in place
__global__ __launch_bounds__(256) void scan2_kernel(int* __restrict__ bsum, int nb) {
  __shared__ int lds[256];
  int tid = threadIdx.x;
  int v = (tid < nb) ? bsum[tid] : 0;
  lds[tid] = v;
  __syncthreads();
  for (int off = 1; off < 256; off <<= 1) {
    int t = (tid >= off) ? lds[tid - off] : 0;
    __syncthreads();
    lds[tid] += t;
    __syncthreads();
  }
  if (tid < nb) bsum[tid] = lds[tid] - v;  // exclusive
}

__global__ __launch_bounds__(256) void scan3_kernel(const int* __restrict__ counts,
                                                    const int* __restrict__ bsum,
                                                    int* __restrict__ offsets, int n) {
  __shared__ int lds[256];
  int tid = threadIdx.x;
  int i = blockIdx.x * 256 + tid;
  int v = (i < n) ? counts[i] : 0;
  lds[tid] = v;
  __syncthreads();
  for (int off = 1; off < 256; off <<= 1) {
    int t = (tid >= off) ? lds[tid - off] : 0;
    __syncthreads();
    lds[tid] += t;
    __syncthreads();
  }
  if (i < n) offsets[i] = bsum[blockIdx.x] + lds[tid] - v;  // exclusive offsets
}

// builds CSR by dst with (src, weight) packed as int2;
// afterwards offsets[v] == segment END (start = end - counts[v])
__global__ __launch_bounds__(256) void scatter_kernel(const int* __restrict__ src,
                                                      const int* __restrict__ dst,
                                                      const float* __restrict__ dinv,
                                                      int* __restrict__ offsets,
                                                      int2* __restrict__ csr_sw, int e) {
  int i = blockIdx.x * 256 + threadIdx.x;
  if (i < e) {
    int d = dst[i], s = src[i];
    int pos = atomicAdd(&offsets[d], 1);
    csr_sw[pos] = make_int2(s, __float_as_int(dinv[s] * dinv[d]));
  }
}

// f32 -> packed bf16 pair (round-to-nearest-even)
__device__ __forceinline__ uint32 bf16pair(float a, float b) {
  uint32 ua = __float_as_uint(a);
  uint32 ub = __float_as_uint(b);
  ua += 0x7fffu + ((ua >> 16) & 1u);
  ub += 0x7fffu + ((ub >> 16) & 1u);
  return (ua >> 16) | (ub & 0xffff0000u);
}

// ---------------- GEMM: T[M x BN](bf16) = X[M x 128](f32) @ W[128 x BN] ----------
// Full-K one-barrier design (R7, measured 51->sub-46 us): stage X^T + full W in
// LDS once, barrier-free k-loop, 4x4 register tile per thread. Output packed
// bf16 (halves gather-source row bytes for the agg that follows).

template <int BM, int BN>
__global__ __launch_bounds__(256) void gemm_kernel(const float* __restrict__ X,
                                                   const float* __restrict__ W,
                                                   uint32* __restrict__ T, int M) {
  constexpr int K = 128;
  static_assert(BM * BN == 4096, "4x4 tile x 256 threads");
  __shared__ float xs[K][BM];   // X^T tile
  __shared__ float ws[K][BN];   // full W

  int tid = threadIdx.x;
  int row0 = blockIdx.x * BM;

  {
    constexpr int TPR = 256 / BM;   // threads per row
    int r = tid / TPR;
    int lw = tid % TPR;
    int grow = row0 + r;
    if (grow >= M) grow = M - 1;    // clamp; garbage rows guarded at store
    const float* xp = &X[(size_t)grow * K];
#pragma unroll
    for (int u = 0; u < K / (4 * TPR); ++u) {
      int k = (lw + u * TPR) * 4;
      float4 v = *(const float4*)&xp[k];
      xs[k + 0][r] = v.x;
      xs[k + 1][r] = v.y;
      xs[k + 2][r] = v.z;
      xs[k + 3][r] = v.w;
    }
  }
  {
    const float4* wsrc = (const float4*)W;
    float4* wdst = (float4*)&ws[0][0];
#pragma unroll
    for (int u = 0; u < (K * BN) / 1024; ++u)
      wdst[tid + u * 256] = wsrc[tid + u * 256];
  }
  __syncthreads();

  int r0 = (tid % (BM / 4)) * 4;
  int c0 = (tid / (BM / 4)) * 4;
  float acc[4][4];
#pragma unroll
  for (int i = 0; i < 4; ++i)
#pragma unroll
    for (int j = 0; j < 4; ++j) acc[i][j] = 0.f;

#pragma unroll 8
  for (int k = 0; k < K; ++k) {
    float4 a = *(const float4*)&xs[k][r0];
    float4 b = *(const float4*)&ws[k][c0];
    float av[4] = {a.x, a.y, a.z, a.w};
    float bv[4] = {b.x, b.y, b.z, b.w};
#pragma unroll
    for (int i = 0; i < 4; ++i)
#pragma unroll
      for (int j = 0; j < 4; ++j) acc[i][j] += av[i] * bv[j];
  }

#pragma unroll
  for (int i = 0; i < 4; ++i) {
    int grow = row0 + r0 + i;
    if (grow < M) {
      uint2 o;
      o.x = bf16pair(acc[i][0], acc[i][1]);
      o.y = bf16pair(acc[i][2], acc[i][3]);
      *(uint2*)&T[((size_t)grow * BN + c0) >> 1] = o;
    }
  }
}

// ---------------- aggregation: O[v] = dinv[v]^2*T[v] + sum_in w*T[src] + b --------
// Full-row gather (R9 structure, 46.6us @ f32): R10 showed feature-slicing
// regresses (line-granularity waste + index re-read); FETCH floor scales with
// row BYTES -> T is bf16 (256B/row @ F=128), halving the coverage floor.
// LPN=F/8 lanes per node, each lane: one uint4 = 8 bf16; 4-wide edge unroll.

template <int F, bool RELU>
__global__ __launch_bounds__(256) void agg_kernel(const uint32* __restrict__ T,
                                                  const int2* __restrict__ csr_sw,
                                                  const int* __restrict__ offsets,
                                                  const int* __restrict__ counts,
                                                  const float* __restrict__ dinv,
                                                  const float* __restrict__ bias,
                                                  float* __restrict__ O, int n) {
  constexpr int LPN = F / 8;     // lanes per node (uint4 = 8 bf16 each)
  constexpr int NPB = 256 / LPN; // nodes per block
  constexpr int RS = F / 8;      // uint4 per row
  int tid = threadIdx.x;
  int lane = tid % LPN;
  int v = blockIdx.x * NPB + tid / LPN;
  if (v >= n) return;

  const uint4* Tv = (const uint4*)T;

#define LO(u) __uint_as_float((u) << 16)
#define HI(u) __uint_as_float((u) & 0xffff0000u)

  float dv = dinv[v];
  float sw = dv * dv;            // self-loop weight
  float a0, a1, a2, a3, a4, a5, a6, a7;
  {
    uint4 q = Tv[(size_t)v * RS + lane];
    a0 = sw * LO(q.x); a1 = sw * HI(q.x);
    a2 = sw * LO(q.y); a3 = sw * HI(q.y);
    a4 = sw * LO(q.z); a5 = sw * HI(q.z);
    a6 = sw * LO(q.w); a7 = sw * HI(q.w);
  }

  int end = offsets[v];
  int i = end - counts[v];
  for (; i + 4 <= end; i += 4) {
    int2 p0 = csr_sw[i + 0];
    int2 p1 = csr_sw[i + 1];
    int2 p2 = csr_sw[i + 2];
    int2 p3 = csr_sw[i + 3];
    uint4 u0 = Tv[(size_t)p0.x * RS + lane];
    uint4 u1 = Tv[(size_t)p1.x * RS + lane];
    uint4 u2 = Tv[(size_t)p2.x * RS + lane];
    uint4 u3 = Tv[(size_t)p3.x * RS + lane];
    float w0 = __int_as_float(p0.y), w1 = __int_as_float(p1.y);
    float w2 = __int_as_float(p2.y), w3 = __int_as_float(p3.y);
    a0 += w0 * LO(u0.x); a1 += w0 * HI(u0.x); a2 += w0 * LO(u0.y); a3 += w0 * HI(u0.y);
    a4 += w0 * LO(u0.z); a5 += w0 * HI(u0.z); a6 += w0 * LO(u0.w); a7 += w0 * HI(u0.w);
    a0 += w1 * LO(u1.x); a1 += w1 * HI(u1.x); a2 += w1 * LO(u1.y); a3 += w1 * HI(u1.y);
    a4 += w1 * LO(u1.z); a5 += w1 * HI(u1.z); a6 += w1 * LO(u1.w); a7 += w1 * HI(u1.w);
    a0 += w2 * LO(u2.x); a1 += w2 * HI(u2.x); a2 += w2 * LO(u2.y); a3 += w2 * HI(u2.y);
    a4 += w2 * LO(u2.z); a5 += w2 * HI(u2.z); a6 += w2 * LO(u2.w); a7 += w2 * HI(u2.w);
    a0 += w3 * LO(u3.x); a1 += w3 * HI(u3.x); a2 += w3 * LO(u3.y); a3 += w3 * HI(u3.y);
    a4 += w3 * LO(u3.z); a5 += w3 * HI(u3.z); a6 += w3 * LO(u3.w); a7 += w3 * HI(u3.w);
  }
  for (; i < end; ++i) {
    int2 p = csr_sw[i];
    float w = __int_as_float(p.y);
    uint4 u = Tv[(size_t)p.x * RS + lane];
    a0 += w * LO(u.x); a1 += w * HI(u.x); a2 += w * LO(u.y); a3 += w * HI(u.y);
    a4 += w * LO(u.z); a5 += w * HI(u.z); a6 += w * LO(u.w); a7 += w * HI(u.w);
  }
#undef LO
#undef HI

  int fo = lane * 8;
  float4 b0 = *(const float4*)&bias[fo];
  float4 b1 = *(const float4*)&bias[fo + 4];
  a0 += b0.x; a1 += b0.y; a2 += b0.z; a3 += b0.w;
  a4 += b1.x; a5 += b1.y; a6 += b1.z; a7 += b1.w;
  if (RELU) {
    a0 = fmaxf(a0, 0.f); a1 = fmaxf(a1, 0.f); a2 = fmaxf(a2, 0.f); a3 = fmaxf(a3, 0.f);
    a4 = fmaxf(a4, 0.f); a5 = fmaxf(a5, 0.f); a6 = fmaxf(a6, 0.f); a7 = fmaxf(a7, 0.f);
  }
  float4 o0 = {a0, a1, a2, a3};
  float4 o1 = {a4, a5, a6, a7};
  *(float4*)&O[(size_t)v * F + fo] = o0;
  *(float4*)&O[(size_t)v * F + fo + 4] = o1;
}

// ---------------- pooling + softmax ----------------

// segmented mean-pool: batch[] is SORTED; per-wave register pre-reduction,
// flush on batch-id change. ~60K atomics vs 3.2M naive (was 264us -> <10us).
__global__ __launch_bounds__(256) void pool_kernel(const float* __restrict__ h3,
                                                   const int* __restrict__ batch,
                                                   float* __restrict__ pooled,
                                                   float* __restrict__ gcnt, int n) {
  constexpr int NPW = 64;  // nodes per wave
  int lane = threadIdx.x & 63;
  int wave = threadIdx.x >> 6;
  int v0 = (blockIdx.x * 4 + wave) * NPW;
  if (v0 >= n) return;
  int vend = min(v0 + NPW, n);

  float acc = 0.f;
  int cnt = 0;
  int bcur = batch[v0];
  for (int v = v0; v < vend; ++v) {
    int b = batch[v];
    if (b != bcur) {
      atomicAdd(&pooled[bcur * 64 + lane], acc);
      if (lane == 0) atomicAdd(&gcnt[bcur], (float)cnt);
      acc = 0.f; cnt = 0; bcur = b;
    }
    acc += h3[(size_t)v * 64 + lane];
    ++cnt;
  }
  atomicAdd(&pooled[bcur * 64 + lane], acc);
  if (lane == 0) atomicAdd(&gcnt[bcur], (float)cnt);
}

__global__ __launch_bounds__(64) void softmax_kernel(const float* __restrict__ pooled,
                                                     const float* __restrict__ gcnt,
                                                     float* __restrict__ out) {
  int g = blockIdx.x;
  int lane = threadIdx.x;
  float c = fmaxf(gcnt[g], 1.0f);
  float v = pooled[g * 64 + lane] / c;
  float m = v;
#pragma unroll
  for (int off = 32; off >= 1; off >>= 1) m = fmaxf(m, __shfl_xor(m, off));
  float e = expf(v - m);
  float s = e;
#pragma unroll
  for (int off = 32; off >= 1; off >>= 1) s += __shfl_xor(s, off);
  out[g * 64 + lane] = e / s;
}

// ---------------- launch ----------------

extern "C" void kernel_launch(void* const* d_in, const int* in_sizes, int n_in,
                              void* d_out, int out_size, void* d_ws, size_t ws_size,
                              hipStream_t stream) {
  const float* x  = (const float*)d_in[0];
  const int* edge = (const int*)d_in[1];
  const int* batch = (const int*)d_in[2];
  const float* W0 = (const float*)d_in[3];
  const float* b0 = (const float*)d_in[4];
  const float* W1 = (const float*)d_in[5];
  const float* b1 = (const float*)d_in[6];
  const float* W2 = (const float*)d_in[7];
  const float* b2 = (const float*)d_in[8];
  float* out = (float*)d_out;

  const int N = in_sizes[2];      // 50000 nodes (batch vector length)
  const int E = in_sizes[1] / 2;  // 600000 edges
  const int* esrc = edge;
  const int* edst = edge + E;

  char* p = (char*)d_ws;
  auto alloc = [&](size_t bytes) {
    char* r = p;
    p += (bytes + 255) & ~(size_t)255;
    return r;
  };
  int*    counts  = (int*)alloc((size_t)N * 4);
  int*    offsets = (int*)alloc((size_t)N * 4);
  float*  dinv    = (float*)alloc((size_t)N * 4);
  int*    bsum    = (int*)alloc(256 * 4);
  int2*   csr_sw  = (int2*)alloc((size_t)E * 8);
  uint32* Tb      = (uint32*)alloc((size_t)N * 128 * 2);  // bf16 gemm output
  float*  A       = (float*)alloc((size_t)N * 128 * 4);   // f32 agg output (ping)
  float*  pooled  = (float*)alloc(128 * 64 * 4);
  float*  gcnt    = (float*)alloc(128 * 4);

  int nbN = (N + 255) / 256;  // 196 (<=256, required by scan2)
  int nbE = (E + 255) / 256;

  hipMemsetAsync(counts, 0, (size_t)N * 4, stream);
  hipMemsetAsync(pooled, 0, 128 * 64 * 4, stream);
  hipMemsetAsync(gcnt, 0, 128 * 4, stream);

  count_kernel<<<nbE, 256, 0, stream>>>(edst, counts, E);
  dinv_kernel<<<nbN, 256, 0, stream>>>(counts, dinv, N);
  scan1_kernel<<<nbN, 256, 0, stream>>>(counts, bsum, N);
  scan2_kernel<<<1, 256, 0, stream>>>(bsum, nbN);
  scan3_kernel<<<nbN, 256, 0, stream>>>(counts, bsum, offsets, N);
  scatter_kernel<<<nbE, 256, 0, stream>>>(esrc, edst, dinv, offsets, csr_sw, E);

  // layer 1: T = x @ W0 (bf16); h1 = relu(A T + b0) (f32)
  gemm_kernel<32, 128><<<(N + 31) / 32, 256, 0, stream>>>(x, W0, Tb, N);
  agg_kernel<128, true><<<(N + 15) / 16, 256, 0, stream>>>(Tb, csr_sw, offsets,
                                                           counts, dinv, b0, A, N);
  // layer 2
  gemm_kernel<32, 128><<<(N + 31) / 32, 256, 0, stream>>>(A, W1, Tb, N);
  agg_kernel<128, true><<<(N + 15) / 16, 256, 0, stream>>>(Tb, csr_sw, offsets,
                                                           counts, dinv, b1, A, N);
  // layer 3 (64-wide, no relu)
  gemm_kernel<64, 64><<<(N + 63) / 64, 256, 0, stream>>>(A, W2, Tb, N);
  agg_kernel<64, false><<<(N + 31) / 32, 256, 0, stream>>>(Tb, csr_sw, offsets,
                                                           counts, dinv, b2, A, N);

  // mean pool + softmax
  pool_kernel<<<(N + 255) / 256, 256, 0, stream>>>(A, batch, pooled, gcnt, N);
  softmax_kernel<<<128, 64, 0, stream>>>(pooled, gcnt, out);
}

// Round 13
// 283.442 us; speedup vs baseline: 1.5218x; 1.1842x over previous
//
#include <hip/hip_runtime.h>
#include <cstdint>
#include <cstddef>

typedef unsigned int uint32;
typedef unsigned short uint16;
using short8 = __attribute__((ext_vector_type(8))) short;
using f32x4 = __attribute__((ext_vector_type(4))) float;

// ---------------- preprocessing kernels ----------------

__global__ __launch_bounds__(256) void count_kernel(const int* __restrict__ dst,
                                                    int* __restrict__ counts, int e) {
  int i = blockIdx.x * 256 + threadIdx.x;
  if (i < e) atomicAdd(&counts[dst[i]], 1);
}

__global__ __launch_bounds__(256) void dinv_kernel(const int* __restrict__ counts,
                                                   float* __restrict__ dinv, int n) {
  int i = blockIdx.x * 256 + threadIdx.x;
  if (i < n) dinv[i] = rsqrtf((float)(counts[i] + 1));  // +1 = self loop
}

__global__ __launch_bounds__(256) void scan1_kernel(const int* __restrict__ counts,
                                                    int* __restrict__ bsum, int n) {
  __shared__ int lds[256];
  int tid = threadIdx.x;
  int i = blockIdx.x * 256 + tid;
  lds[tid] = (i < n) ? counts[i] : 0;
  __syncthreads();
  for (int off = 128; off > 0; off >>= 1) {
    if (tid < off) lds[tid] += lds[tid + off];
    __syncthreads();
  }
  if (tid == 0) bsum[blockIdx.x] = lds[0];
}

// exclusive scan of nb (<=256) block sums, in place
__global__ __launch_bounds__(256) void scan2_kernel(int* __restrict__ bsum, int nb) {
  __shared__ int lds[256];
  int tid = threadIdx.x;
  int v = (tid < nb) ? bsum[tid] : 0;
  lds[tid] = v;
  __syncthreads();
  for (int off = 1; off < 256; off <<= 1) {
    int t = (tid >= off) ? lds[tid - off] : 0;
    __syncthreads();
    lds[tid] += t;
    __syncthreads();
  }
  if (tid < nb) bsum[tid] = lds[tid] - v;  // exclusive
}

__global__ __launch_bounds__(256) void scan3_kernel(const int* __restrict__ counts,
                                                    const int* __restrict__ bsum,
                                                    int* __restrict__ offsets, int n) {
  __shared__ int lds[256];
  int tid = threadIdx.x;
  int i = blockIdx.x * 256 + tid;
  int v = (i < n) ? counts[i] : 0;
  lds[tid] = v;
  __syncthreads();
  for (int off = 1; off < 256; off <<= 1) {
    int t = (tid >= off) ? lds[tid - off] : 0;
    __syncthreads();
    lds[tid] += t;
    __syncthreads();
  }
  if (i < n) offsets[i] = bsum[blockIdx.x] + lds[tid] - v;  // exclusive offsets
}

// builds CSR by dst with (src, weight) packed as int2;
// afterwards offsets[v] == segment END (start = end - counts[v])
__global__ __launch_bounds__(256) void scatter_kernel(const int* __restrict__ src,
                                                      const int* __restrict__ dst,
                                                      const float* __restrict__ dinv,
                                                      int* __restrict__ offsets,
                                                      int2* __restrict__ csr_sw, int e) {
  int i = blockIdx.x * 256 + threadIdx.x;
  if (i < e) {
    int d = dst[i], s = src[i];
    int pos = atomicAdd(&offsets[d], 1);
    csr_sw[pos] = make_int2(s, __float_as_int(dinv[s] * dinv[d]));
  }
}

// f32 -> bf16 (round-to-nearest-even)
__device__ __forceinline__ uint32 bf16of(float a) {
  uint32 u = __float_as_uint(a);
  u += 0x7fffu + ((u >> 16) & 1u);
  return u >> 16;
}
__device__ __forceinline__ uint32 bf16pair(float a, float b) {
  return bf16of(a) | (bf16of(b) << 16);
}

// transpose+cast the three weight matrices W[k][col](f32) -> Wt[col][k](bf16,
// packed as uint32 k-pairs). One launch: blocks [0,32) W0, [32,64) W1, [64,80) W2.
__global__ __launch_bounds__(256) void wprep_kernel(const float* __restrict__ W0,
                                                    const float* __restrict__ W1,
                                                    const float* __restrict__ W2,
                                                    uint32* __restrict__ Wt0,
                                                    uint32* __restrict__ Wt1,
                                                    uint32* __restrict__ Wt2) {
  int b = blockIdx.x;
  const float* W; uint32* Wt; int N; int base;
  if (b < 32)      { W = W0; Wt = Wt0; N = 128; base = b; }
  else if (b < 64) { W = W1; Wt = Wt1; N = 128; base = b - 32; }
  else             { W = W2; Wt = Wt2; N = 64;  base = b - 64; }
  int id = base * 256 + threadIdx.x;   // (col, kpair), col fastest (coalesced reads)
  int col = id % N;
  int kp = id / N;
  if (kp >= 64) return;
  int k = kp * 2;
  Wt[col * 64 + kp] = bf16pair(W[(size_t)k * N + col], W[(size_t)(k + 1) * N + col]);
}

// ---------------- GEMM (MFMA): T[M x BN](bf16) = X[M x 128](f32) @ W ----------
// bf16 v_mfma_f32_16x16x32: 4 waves/block, each wave one 16-row strip of a
// 64-row tile; NT = BN/16 col-tiles; K=128 = 4 k-chunks; f32 accumulate.
// X and W^T staged in LDS as bf16 with XOR swizzle byte^=((row&7)<<4) to kill
// the 256B-row-stride bank conflict on fragment ds_read_b128 (Guideline 4).
// Fragment maps (m89-verified C/D): A row=lane&15,k=(lane>>4)*8+j;
// B col=lane&15, same k; D col=lane&15, row=(lane>>4)*4+reg.

template <int BN>
__global__ __launch_bounds__(256) void gemm_kernel(const float* __restrict__ X,
                                                   const uint32* __restrict__ Wt,
                                                   uint16* __restrict__ T, int M) {
  constexpr int K = 128, BM = 64;
  constexpr int NT = BN / 16;
  __shared__ alignas(16) uint16 xs[BM * K];    // swizzled bf16 X tile (256B rows)
  __shared__ alignas(16) uint16 wsT[BN * K];   // swizzled bf16 W^T (256B rows)

  int tid = threadIdx.x;
  int row0 = blockIdx.x * BM;

  // stage X: thread -> (row = tid>>2, k0 = (tid&3)*32); 8x float4 -> bf16x4 pairs
  {
    int r = tid >> 2, k0 = (tid & 3) * 32;
    int grow = row0 + r;
    if (grow >= M) grow = M - 1;               // clamp; stores guarded later
    const float* xp = &X[(size_t)grow * K];
#pragma unroll
    for (int u = 0; u < 8; ++u) {
      int k = k0 + u * 4;
      float4 v = *(const float4*)&xp[k];
      uint2 pk = make_uint2(bf16pair(v.x, v.y), bf16pair(v.z, v.w));
      int byte = (r * 256 + k * 2) ^ ((r & 7) << 4);
      *(uint2*)((char*)xs + byte) = pk;
    }
  }
  // stage W^T: linear 16B copy from global Wt with swizzled destination
  {
#pragma unroll
    for (int u = 0; u < NT; ++u) {
      int idx = tid + u * 256;                 // 16B unit; 16 units per 256B row
      int col = idx >> 4;
      int kb = (idx & 15) << 4;
      uint4 v = *(const uint4*)((const char*)Wt + col * 256 + kb);
      int byte = (col * 256 + kb) ^ ((col & 7) << 4);
      *(uint4*)((char*)wsT + byte) = v;
    }
  }
  __syncthreads();

  int w = tid >> 6, l = tid & 63;
  int lrow = l & 15, lk = l >> 4;

  f32x4 acc[NT];
#pragma unroll
  for (int n = 0; n < NT; ++n) acc[n] = {0.f, 0.f, 0.f, 0.f};

#pragma unroll
  for (int c = 0; c < 4; ++c) {
    int ak = c * 32 + lk * 8;                  // 8 consecutive k
    int ar = w * 16 + lrow;                    // A row
    short8 afrag = *(const short8*)((const char*)xs + ((ar * 256 + ak * 2) ^ ((ar & 7) << 4)));
#pragma unroll
    for (int n = 0; n < NT; ++n) {
      int bc = n * 16 + lrow;                  // B col
      short8 bfrag = *(const short8*)((const char*)wsT + ((bc * 256 + ak * 2) ^ ((bc & 7) << 4)));
      acc[n] = __builtin_amdgcn_mfma_f32_16x16x32_bf16(afrag, bfrag, acc[n], 0, 0, 0);
    }
  }

  // epilogue: D col = lane&15, row = lk*4 + reg; write bf16 (2B, coalesced 32B/16 lanes)
#pragma unroll
  for (int n = 0; n < NT; ++n) {
#pragma unroll
    for (int r = 0; r < 4; ++r) {
      int grow = row0 + w * 16 + lk * 4 + r;
      if (grow < M)
        T[(size_t)grow * BN + n * 16 + lrow] = (uint16)bf16of(acc[n][r]);
    }
  }
}

// ---------------- aggregation: O[v] = dinv[v]^2*T[v] + sum_in w*T[src] + b --------
// Full-row gather over bf16 T (R12-measured win: coverage floor scales with row
// bytes). LPN=F/8 lanes per node, each lane one uint4 = 8 bf16; 4-wide unroll.

template <int F, bool RELU>
__global__ __launch_bounds__(256) void agg_kernel(const uint32* __restrict__ T,
                                                  const int2* __restrict__ csr_sw,
                                                  const int* __restrict__ offsets,
                                                  const int* __restrict__ counts,
                                                  const float* __restrict__ dinv,
                                                  const float* __restrict__ bias,
                                                  float* __restrict__ O, int n) {
  constexpr int LPN = F / 8;     // lanes per node (uint4 = 8 bf16 each)
  constexpr int NPB = 256 / LPN; // nodes per block
  constexpr int RS = F / 8;      // uint4 per row
  int tid = threadIdx.x;
  int lane = tid % LPN;
  int v = blockIdx.x * NPB + tid / LPN;
  if (v >= n) return;

  const uint4* Tv = (const uint4*)T;

#define LO(u) __uint_as_float((u) << 16)
#define HI(u) __uint_as_float((u) & 0xffff0000u)

  float dv = dinv[v];
  float sw = dv * dv;            // self-loop weight
  float a0, a1, a2, a3, a4, a5, a6, a7;
  {
    uint4 q = Tv[(size_t)v * RS + lane];
    a0 = sw * LO(q.x); a1 = sw * HI(q.x);
    a2 = sw * LO(q.y); a3 = sw * HI(q.y);
    a4 = sw * LO(q.z); a5 = sw * HI(q.z);
    a6 = sw * LO(q.w); a7 = sw * HI(q.w);
  }

  int end = offsets[v];
  int i = end - counts[v];
  for (; i + 4 <= end; i += 4) {
    int2 p0 = csr_sw[i + 0];
    int2 p1 = csr_sw[i + 1];
    int2 p2 = csr_sw[i + 2];
    int2 p3 = csr_sw[i + 3];
    uint4 u0 = Tv[(size_t)p0.x * RS + lane];
    uint4 u1 = Tv[(size_t)p1.x * RS + lane];
    uint4 u2 = Tv[(size_t)p2.x * RS + lane];
    uint4 u3 = Tv[(size_t)p3.x * RS + lane];
    float w0 = __int_as_float(p0.y), w1 = __int_as_float(p1.y);
    float w2 = __int_as_float(p2.y), w3 = __int_as_float(p3.y);
    a0 += w0 * LO(u0.x); a1 += w0 * HI(u0.x); a2 += w0 * LO(u0.y); a3 += w0 * HI(u0.y);
    a4 += w0 * LO(u0.z); a5 += w0 * HI(u0.z); a6 += w0 * LO(u0.w); a7 += w0 * HI(u0.w);
    a0 += w1 * LO(u1.x); a1 += w1 * HI(u1.x); a2 += w1 * LO(u1.y); a3 += w1 * HI(u1.y);
    a4 += w1 * LO(u1.z); a5 += w1 * HI(u1.z); a6 += w1 * LO(u1.w); a7 += w1 * HI(u1.w);
    a0 += w2 * LO(u2.x); a1 += w2 * HI(u2.x); a2 += w2 * LO(u2.y); a3 += w2 * HI(u2.y);
    a4 += w2 * LO(u2.z); a5 += w2 * HI(u2.z); a6 += w2 * LO(u2.w); a7 += w2 * HI(u2.w);
    a0 += w3 * LO(u3.x); a1 += w3 * HI(u3.x); a2 += w3 * LO(u3.y); a3 += w3 * HI(u3.y);
    a4 += w3 * LO(u3.z); a5 += w3 * HI(u3.z); a6 += w3 * LO(u3.w); a7 += w3 * HI(u3.w);
  }
  for (; i < end; ++i) {
    int2 p = csr_sw[i];
    float w = __int_as_float(p.y);
    uint4 u = Tv[(size_t)p.x * RS + lane];
    a0 += w * LO(u.x); a1 += w * HI(u.x); a2 += w * LO(u.y); a3 += w * HI(u.y);
    a4 += w * LO(u.z); a5 += w * HI(u.z); a6 += w * LO(u.w); a7 += w * HI(u.w);
  }
#undef LO
#undef HI

  int fo = lane * 8;
  float4 b0 = *(const float4*)&bias[fo];
  float4 b1 = *(const float4*)&bias[fo + 4];
  a0 += b0.x; a1 += b0.y; a2 += b0.z; a3 += b0.w;
  a4 += b1.x; a5 += b1.y; a6 += b1.z; a7 += b1.w;
  if (RELU) {
    a0 = fmaxf(a0, 0.f); a1 = fmaxf(a1, 0.f); a2 = fmaxf(a2, 0.f); a3 = fmaxf(a3, 0.f);
    a4 = fmaxf(a4, 0.f); a5 = fmaxf(a5, 0.f); a6 = fmaxf(a6, 0.f); a7 = fmaxf(a7, 0.f);
  }
  float4 o0 = {a0, a1, a2, a3};
  float4 o1 = {a4, a5, a6, a7};
  *(float4*)&O[(size_t)v * F + fo] = o0;
  *(float4*)&O[(size_t)v * F + fo + 4] = o1;
}

// ---------------- pooling + softmax ----------------

// segmented mean-pool: batch[] is SORTED; per-wave register pre-reduction,
// flush on batch-id change. ~60K atomics vs 3.2M naive (was 264us -> <10us).
__global__ __launch_bounds__(256) void pool_kernel(const float* __restrict__ h3,
                                                   const int* __restrict__ batch,
                                                   float* __restrict__ pooled,
                                                   float* __restrict__ gcnt, int n) {
  constexpr int NPW = 64;  // nodes per wave
  int lane = threadIdx.x & 63;
  int wave = threadIdx.x >> 6;
  int v0 = (blockIdx.x * 4 + wave) * NPW;
  if (v0 >= n) return;
  int vend = min(v0 + NPW, n);

  float acc = 0.f;
  int cnt = 0;
  int bcur = batch[v0];
  for (int v = v0; v < vend; ++v) {
    int b = batch[v];
    if (b != bcur) {
      atomicAdd(&pooled[bcur * 64 + lane], acc);
      if (lane == 0) atomicAdd(&gcnt[bcur], (float)cnt);
      acc = 0.f; cnt = 0; bcur = b;
    }
    acc += h3[(size_t)v * 64 + lane];
    ++cnt;
  }
  atomicAdd(&pooled[bcur * 64 + lane], acc);
  if (lane == 0) atomicAdd(&gcnt[bcur], (float)cnt);
}

__global__ __launch_bounds__(64) void softmax_kernel(const float* __restrict__ pooled,
                                                     const float* __restrict__ gcnt,
                                                     float* __restrict__ out) {
  int g = blockIdx.x;
  int lane = threadIdx.x;
  float c = fmaxf(gcnt[g], 1.0f);
  float v = pooled[g * 64 + lane] / c;
  float m = v;
#pragma unroll
  for (int off = 32; off >= 1; off >>= 1) m = fmaxf(m, __shfl_xor(m, off));
  float e = expf(v - m);
  float s = e;
#pragma unroll
  for (int off = 32; off >= 1; off >>= 1) s += __shfl_xor(s, off);
  out[g * 64 + lane] = e / s;
}

// ---------------- launch ----------------

extern "C" void kernel_launch(void* const* d_in, const int* in_sizes, int n_in,
                              void* d_out, int out_size, void* d_ws, size_t ws_size,
                              hipStream_t stream) {
  const float* x  = (const float*)d_in[0];
  const int* edge = (const int*)d_in[1];
  const int* batch = (const int*)d_in[2];
  const float* W0 = (const float*)d_in[3];
  const float* b0 = (const float*)d_in[4];
  const float* W1 = (const float*)d_in[5];
  const float* b1 = (const float*)d_in[6];
  const float* W2 = (const float*)d_in[7];
  const float* b2 = (const float*)d_in[8];
  float* out = (float*)d_out;

  const int N = in_sizes[2];      // 50000 nodes (batch vector length)
  const int E = in_sizes[1] / 2;  // 600000 edges
  const int* esrc = edge;
  const int* edst = edge + E;

  char* p = (char*)d_ws;
  auto alloc = [&](size_t bytes) {
    char* r = p;
    p += (bytes + 255) & ~(size_t)255;
    return r;
  };
  int*    counts  = (int*)alloc((size_t)N * 4);
  int*    offsets = (int*)alloc((size_t)N * 4);
  float*  dinv    = (float*)alloc((size_t)N * 4);
  int*    bsum    = (int*)alloc(256 * 4);
  int2*   csr_sw  = (int2*)alloc((size_t)E * 8);
  uint16* Tb      = (uint16*)alloc((size_t)N * 128 * 2);  // bf16 gemm output
  float*  A       = (float*)alloc((size_t)N * 128 * 4);   // f32 agg output (ping)
  uint32* Wt0     = (uint32*)alloc(128 * 64 * 4);         // W^T bf16-packed
  uint32* Wt1     = (uint32*)alloc(128 * 64 * 4);
  uint32* Wt2     = (uint32*)alloc(64 * 64 * 4);
  float*  pooled  = (float*)alloc(128 * 64 * 4);
  float*  gcnt    = (float*)alloc(128 * 4);

  int nbN = (N + 255) / 256;  // 196 (<=256, required by scan2)
  int nbE = (E + 255) / 256;

  hipMemsetAsync(counts, 0, (size_t)N * 4, stream);
  hipMemsetAsync(pooled, 0, 128 * 64 * 4, stream);
  hipMemsetAsync(gcnt, 0, 128 * 4, stream);

  count_kernel<<<nbE, 256, 0, stream>>>(edst, counts, E);
  dinv_kernel<<<nbN, 256, 0, stream>>>(counts, dinv, N);
  scan1_kernel<<<nbN, 256, 0, stream>>>(counts, bsum, N);
  scan2_kernel<<<1, 256, 0, stream>>>(bsum, nbN);
  scan3_kernel<<<nbN, 256, 0, stream>>>(counts, bsum, offsets, N);
  scatter_kernel<<<nbE, 256, 0, stream>>>(esrc, edst, dinv, offsets, csr_sw, E);
  wprep_kernel<<<80, 256, 0, stream>>>(W0, W1, W2, Wt0, Wt1, Wt2);

  int nbG = (N + 63) / 64;

  // layer 1: T = x @ W0 (bf16 mfma); h1 = relu(A T + b0) (f32)
  gemm_kernel<128><<<nbG, 256, 0, stream>>>(x, Wt0, Tb, N);
  agg_kernel<128, true><<<(N + 15) / 16, 256, 0, stream>>>((const uint32*)Tb, csr_sw,
                                                           offsets, counts, dinv, b0, A, N);
  // layer 2
  gemm_kernel<128><<<nbG, 256, 0, stream>>>(A, Wt1, Tb, N);
  agg_kernel<128, true><<<(N + 15) / 16, 256, 0, stream>>>((const uint32*)Tb, csr_sw,
                                                           offsets, counts, dinv, b1, A, N);
  // layer 3 (64-wide, no relu)
  gemm_kernel<64><<<nbG, 256, 0, stream>>>(A, Wt2, Tb, N);
  agg_kernel<64, false><<<(N + 31) / 32, 256, 0, stream>>>((const uint32*)Tb, csr_sw,
                                                           offsets, counts, dinv, b2, A, N);

  // mean pool + softmax
  pool_kernel<<<(N + 255) / 256, 256, 0, stream>>>(A, batch, pooled, gcnt, N);
  softmax_kernel<<<128, 64, 0, stream>>>(pooled, gcnt, out);
}